// Round 11
// baseline (402.578 us; speedup 1.0000x reference)
//
#include <hip/hip_runtime.h>
#include <hip/hip_bf16.h>
#include <math.h>

#define B_ 2
#define T_ 1024
#define D_ 256
#define N_ 1024
#define H_ 8
#define HD_ 128
#define K_ 32
#define VOCAB_ 32000

typedef __attribute__((ext_vector_type(8))) short short8v;
typedef __attribute__((ext_vector_type(4))) float f32x4;

static __device__ __forceinline__ float geluf(float x) {
    return 0.5f * x * (1.0f + erff(x * 0.70710678118654752f));
}

static __device__ __forceinline__ ushort f2bf(float f) {
    unsigned u = __builtin_bit_cast(unsigned, f);
    u += 0x7fff + ((u >> 16) & 1);
    return (ushort)(u >> 16);
}

static __device__ __forceinline__ float bf2f(ushort u) {
    unsigned v = ((unsigned)u) << 16;
    return __builtin_bit_cast(float, v);
}

// ---------------- batched transpose-cast descriptors ----------------
struct TcastBatch {
    const float* in[9];
    ushort* out[9];
    long inS[9], outS[9];
    int cb[9], rb[9], R[9], C[9];
    int cum[10];
};

// ---------------- prep: embed+RoPE+LN blocks || all weight tcasts ----------------
__global__ __launch_bounds__(256) void prep_kernel(
    TcastBatch tb,
    const int* __restrict__ tokens, const float* __restrict__ emb,
    const float* __restrict__ field_init,
    const float* __restrict__ g1, const float* __restrict__ b1,
    const float* __restrict__ g2, const float* __restrict__ b2,
    float* __restrict__ x, ushort* __restrict__ y1, ushort* __restrict__ y2) {
    __shared__ float sm[64][65];
    int bid = blockIdx.x;
    if (bid < B_ * T_) {
        int bt = bid;
        int d = threadIdx.x;
        int t = bt & (T_ - 1);
        int tok = tokens[bt];
        float v = emb[(long)tok * D_ + d] + field_init[d];
        float partner = __shfl_xor(v, 1);
        float rot = (d & 1) ? partner : -partner;
        float freq = exp2f(-0.0625f * (float)(d & ~1)) * (1.0f / 6.283185307179586f);
        float ph = fmodf((float)t * freq, 1.0f) * 6.283185307179586f;
        v = v * cosf(ph) + rot * sinf(ph);
        long i = (long)bt * D_ + d;
        x[i] = v;
        float* red = sm[0];
        int lane = d & 63, wid = d >> 6;
        float s = v;
        #pragma unroll
        for (int off = 32; off; off >>= 1) s += __shfl_xor(s, off);
        if (lane == 0) red[wid] = s;
        __syncthreads();
        float mu = (red[0] + red[1] + red[2] + red[3]) * (1.0f / D_);
        float dv = v - mu;
        float s2 = dv * dv;
        #pragma unroll
        for (int off = 32; off; off >>= 1) s2 += __shfl_xor(s2, off);
        __syncthreads();
        if (lane == 0) red[wid] = s2;
        __syncthreads();
        float var = (red[0] + red[1] + red[2] + red[3]) * (1.0f / D_);
        float rstd = rsqrtf(var + 1e-5f);
        float nv = dv * rstd;
        y1[i] = f2bf(nv * g1[d] + b1[d]);
        y2[i] = f2bf(nv * g2[d] + b2[d]);
        return;
    }
    bid -= B_ * T_;
    int dsc = 0;
    #pragma unroll
    for (int i = 0; i < 9; ++i) if (bid >= tb.cum[i + 1]) dsc = i + 1;
    int local = bid - tb.cum[dsc];
    int bpz = tb.cb[dsc] * tb.rb[dsc];
    int z = local / bpz;
    int rem = local - z * bpz;
    int cx = rem % tb.cb[dsc], ry = rem / tb.cb[dsc];
    const float* in = tb.in[dsc] + z * tb.inS[dsc];
    ushort* out = tb.out[dsc] + z * tb.outS[dsc];
    int R = tb.R[dsc], C = tb.C[dsc];
    int r0 = ry * 64, c0 = cx * 64;
    int tx = threadIdx.x & 63, ty = threadIdx.x >> 6;
    #pragma unroll
    for (int i = 0; i < 16; ++i) {
        int r = i * 4 + ty;
        sm[r][tx] = in[(long)(r0 + r) * C + c0 + tx];
    }
    __syncthreads();
    #pragma unroll
    for (int i = 0; i < 16; ++i) {
        int c = i * 4 + ty;
        out[(long)(c0 + c) * R + r0 + tx] = f2bf(sm[tx][c]);
    }
}

// ---------------- LayerNorm (+ optional residual add of dx) -> bf16 outputs ------
__global__ void ln_kernel(float* __restrict__ x, const float* __restrict__ dx,
                          const float* __restrict__ g1, const float* __restrict__ b1,
                          const float* __restrict__ g2, const float* __restrict__ b2,
                          ushort* __restrict__ y1, ushort* __restrict__ y2) {
    int row = blockIdx.x;
    int d = threadIdx.x;
    long i = (long)row * D_ + d;
    float v = x[i] + dx[i];
    x[i] = v;
    __shared__ float red[4];
    int lane = d & 63, wid = d >> 6;
    float s = v;
    #pragma unroll
    for (int off = 32; off; off >>= 1) s += __shfl_xor(s, off);
    if (lane == 0) red[wid] = s;
    __syncthreads();
    float mu = (red[0] + red[1] + red[2] + red[3]) * (1.0f / D_);
    float dv = v - mu;
    float s2 = dv * dv;
    #pragma unroll
    for (int off = 32; off; off >>= 1) s2 += __shfl_xor(s2, off);
    __syncthreads();
    if (lane == 0) red[wid] = s2;
    __syncthreads();
    float var = (red[0] + red[1] + red[2] + red[3]) * (1.0f / D_);
    float rstd = rsqrtf(var + 1e-5f);
    float nv = dv * rstd;
    y1[i] = f2bf(nv * g1[d] + b1[d]);
    if (y2) y2[i] = f2bf(nv * g2[d] + b2[d]);
}

// ================= 128x128 MFMA core, BK=64; LDS-staged epilogue =============
#define LDK 72
#define CSTR 132

template<int ACT, int OUTBF, int SIG>
__device__ __forceinline__ void gemm128_core(
    const ushort* __restrict__ A, int lda,
    const ushort* __restrict__ Bt, int ldb,
    const float* __restrict__ bias, void* __restrict__ Cout, int ldc,
    int Kd, int bx, int by,
    float* __restrict__ psOut, float* __restrict__ ps8Out) {
    __shared__ __align__(16) ushort As[128 * LDK];
    __shared__ __align__(16) ushort Bs[128 * LDK];
    int tid = threadIdx.x;
    int wid = tid >> 6, lane = tid & 63;
    int brow = by * 128, bcol = bx * 128;
    int wr = wid >> 1, wc = wid & 1;
    f32x4 acc[4][4] = {};
    for (int k0 = 0; k0 < Kd; k0 += 64) {
        __syncthreads();
        #pragma unroll
        for (int j = 0; j < 4; ++j) {
            int idx = tid + j * 256;
            int r = idx >> 3, sgm = idx & 7;
            *(short8v*)&As[r * LDK + sgm * 8] =
                *(const short8v*)&A[(long)(brow + r) * lda + k0 + sgm * 8];
            *(short8v*)&Bs[r * LDK + sgm * 8] =
                *(const short8v*)&Bt[(long)(bcol + r) * ldb + k0 + sgm * 8];
        }
        __syncthreads();
        #pragma unroll
        for (int kk = 0; kk < 2; ++kk) {
            short8v af[4], bfv[4];
            #pragma unroll
            for (int m = 0; m < 4; ++m)
                af[m] = *(const short8v*)&As[(wr * 64 + m * 16 + (lane & 15)) * LDK + kk * 32 + (lane >> 4) * 8];
            #pragma unroll
            for (int n = 0; n < 4; ++n)
                bfv[n] = *(const short8v*)&Bs[(wc * 64 + n * 16 + (lane & 15)) * LDK + kk * 32 + (lane >> 4) * 8];
            #pragma unroll
            for (int m = 0; m < 4; ++m)
                #pragma unroll
                for (int n = 0; n < 4; ++n)
                    acc[m][n] = __builtin_amdgcn_mfma_f32_16x16x32_bf16(af[m], bfv[n], acc[m][n], 0, 0, 0);
        }
    }
    float* Cs = (float*)As;
    float cs = 0.f, cs8 = 0.f;
    #pragma unroll
    for (int chunk = 0; chunk < 4; ++chunk) {
        __syncthreads();
        if (wr == (chunk >> 1)) {
            #pragma unroll
            for (int mm = 0; mm < 2; ++mm) {
                int m = (chunk & 1) * 2 + mm;
                int lr0 = mm * 16 + ((lane >> 4) << 2);
                #pragma unroll
                for (int n = 0; n < 4; ++n) {
                    int lcol = wc * 64 + n * 16 + (lane & 15);
                    #pragma unroll
                    for (int j = 0; j < 4; ++j)
                        Cs[(lr0 + j) * CSTR + lcol] = acc[m][n][j];
                }
            }
        }
        __syncthreads();
        int lrow = tid >> 3, f4 = tid & 7;
        long grow = brow + chunk * 32 + lrow;
        if (OUTBF) {
            #pragma unroll
            for (int u = 0; u < 2; ++u) {
                int c0i = (f4 + u * 8) * 8;
                uint pk[4];
                #pragma unroll
                for (int q = 0; q < 4; ++q) {
                    int cc = c0i + 2 * q;
                    float v0 = Cs[lrow * CSTR + cc]     + (bias ? bias[bcol + cc] : 0.0f);
                    float v1 = Cs[lrow * CSTR + cc + 1] + (bias ? bias[bcol + cc + 1] : 0.0f);
                    if (ACT == 1) { v0 = fmaxf(v0, 0.0f); v1 = fmaxf(v1, 0.0f); }
                    else if (ACT == 2) { v0 = geluf(v0); v1 = geluf(v1); }
                    pk[q] = (uint)f2bf(v0) | ((uint)f2bf(v1) << 16);
                }
                *(uint4*)&((ushort*)Cout)[grow * ldc + bcol + c0i] = *(uint4*)pk;
            }
        } else {
            #pragma unroll
            for (int u = 0; u < 4; ++u) {
                int c0i = (f4 + u * 8) * 4;
                f32x4 vv;
                #pragma unroll
                for (int q = 0; q < 4; ++q) {
                    float v = Cs[lrow * CSTR + c0i + q] + (bias ? bias[bcol + c0i + q] : 0.0f);
                    if (ACT == 1) v = fmaxf(v, 0.0f);
                    else if (ACT == 2) v = geluf(v);
                    vv[q] = v;
                }
                *(f32x4*)&((float*)Cout)[grow * ldc + bcol + c0i] = vv;
            }
        }
        if (SIG && tid < 128) {
            #pragma unroll
            for (int r = 0; r < 32; ++r) {
                float vr = fmaxf(Cs[r * CSTR + tid], 0.0f);
                cs += vr;
                if ((r & 7) == 0) cs8 += vr;
            }
        }
    }
    if (SIG && tid < 128) {
        psOut[by * 1024 + bcol + tid] = cs;
        ps8Out[by * 1024 + bcol + tid] = cs8;
    }
}

// batched qs/vs/ffn1 (bf16 out); z=0 also emits sig partial sums
__global__ __launch_bounds__(256) void gemm3_kernel(
    const ushort* __restrict__ y1, const ushort* __restrict__ y2,
    const ushort* __restrict__ WqT, const ushort* __restrict__ WvT, const ushort* __restrict__ fW1T,
    const float* __restrict__ fb1,
    ushort* __restrict__ qs, ushort* __restrict__ vs, ushort* __restrict__ ffnh,
    float* __restrict__ ps, float* __restrict__ ps8) {
    int z = blockIdx.z;
    if (z == 0)
        gemm128_core<1, 1, 1>(y1, 256, WqT, 256, nullptr, qs, 1024, 256,
                              blockIdx.x, blockIdx.y, ps, ps8);
    else if (z == 1)
        gemm128_core<1, 1, 0>(y1, 256, WvT, 256, nullptr, vs, 1024, 256,
                              blockIdx.x, blockIdx.y, nullptr, nullptr);
    else
        gemm128_core<2, 1, 0>(y2, 256, fW1T, 256, fb1, ffnh, 1024, 256,
                              blockIdx.x, blockIdx.y, nullptr, nullptr);
}

// vocab projection, XCD-chunked swizzle (grid 4000 = 8*500)
__global__ __launch_bounds__(256) void vocab_kernel(
    const ushort* __restrict__ yf, const ushort* __restrict__ WlT,
    const float* __restrict__ bl, float* __restrict__ out) {
    int g = blockIdx.x;
    int nid = (g & 7) * 500 + (g >> 3);
    gemm128_core<0, 0, 0>(yf, 256, WlT, 256, bl, out, VOCAB_, 256,
                          nid >> 4, nid & 15, nullptr, nullptr);
}

// ===== merged decoder+FFN2: dx = [gated|ffnh](K=2048) @ [decT;fW2T]^T + fb2 =====
__global__ __launch_bounds__(256) void gemm2b_kernel(
    const ushort* __restrict__ gated, const ushort* __restrict__ ffnh,
    const ushort* __restrict__ decT, const ushort* __restrict__ fW2T,
    const float* __restrict__ fb2, float* __restrict__ dx) {
    const int N = 256;
    __shared__ __align__(16) ushort As[64 * LDK];
    __shared__ __align__(16) ushort Bs[64 * LDK];
    int tid = threadIdx.x;
    int wid = tid >> 6, lane = tid & 63;
    int brow = blockIdx.y * 64, bcol = blockIdx.x * 64;
    int wr = wid >> 1, wc = wid & 1;
    f32x4 acc[2][2] = {};
    for (int k0 = 0; k0 < 2048; k0 += 64) {
        const ushort* Asrc = (k0 < 1024) ? gated : ffnh;
        const ushort* Bsrc = (k0 < 1024) ? decT : fW2T;
        int kk0 = k0 & 1023;
        __syncthreads();
        #pragma unroll
        for (int j = 0; j < 2; ++j) {
            int idx = tid + j * 256;
            int r = idx >> 3, sgm = idx & 7;
            *(short8v*)&As[r * LDK + sgm * 8] =
                *(const short8v*)&Asrc[(long)(brow + r) * 1024 + kk0 + sgm * 8];
            *(short8v*)&Bs[r * LDK + sgm * 8] =
                *(const short8v*)&Bsrc[(long)(bcol + r) * 1024 + kk0 + sgm * 8];
        }
        __syncthreads();
        #pragma unroll
        for (int kk = 0; kk < 2; ++kk) {
            short8v af[2], bfv[2];
            #pragma unroll
            for (int m = 0; m < 2; ++m)
                af[m] = *(const short8v*)&As[(wr * 32 + m * 16 + (lane & 15)) * LDK + kk * 32 + (lane >> 4) * 8];
            #pragma unroll
            for (int n = 0; n < 2; ++n)
                bfv[n] = *(const short8v*)&Bs[(wc * 32 + n * 16 + (lane & 15)) * LDK + kk * 32 + (lane >> 4) * 8];
            #pragma unroll
            for (int m = 0; m < 2; ++m)
                #pragma unroll
                for (int n = 0; n < 2; ++n)
                    acc[m][n] = __builtin_amdgcn_mfma_f32_16x16x32_bf16(af[m], bfv[n], acc[m][n], 0, 0, 0);
        }
    }
    int r0 = brow + wr * 32 + ((lane >> 4) << 2);
    int c0 = bcol + wc * 32 + (lane & 15);
    #pragma unroll
    for (int n = 0; n < 2; ++n) {
        int col = c0 + n * 16;
        float bv = fb2[col];
        #pragma unroll
        for (int m = 0; m < 2; ++m)
            #pragma unroll
            for (int j = 0; j < 4; ++j)
                dx[(long)(r0 + m * 16 + j) * N + col] = acc[m][n][j] + bv;
    }
}

// ---------------- fused metric MLP: sig-reduce + hid + metric ----------------
__global__ __launch_bounds__(1024) void mlpf_kernel(
    const float* __restrict__ ps, const float* __restrict__ ps8,
    const ushort* __restrict__ mW1T, const float* __restrict__ mb1,
    const ushort* __restrict__ mW2T, const float* __restrict__ mb2,
    const float* __restrict__ base_metric, float* __restrict__ metric) {
    int blk = blockIdx.x;
    int b = blk >> 4, sub = blk & 15;
    __shared__ float sig_l[1024];
    __shared__ float hid_l[512];
    int tid = threadIdx.x;
    {
        float s = 0.f, s8 = 0.f;
        #pragma unroll
        for (int by8 = 0; by8 < 8; ++by8) {
            s += ps[(b * 8 + by8) * 1024 + tid];
            s8 += ps8[(b * 8 + by8) * 1024 + tid];
        }
        sig_l[tid] = s * (1.0f / 1024.0f) + 0.5f * s8 * (1.0f / 128.0f);
    }
    __syncthreads();
    int w = tid >> 6, lane = tid & 63;
    for (int jj = 0; jj < 32; ++jj) {
        int j = w * 32 + jj;
        const ushort* wrow = mW1T + (long)j * 1024;
        float acc = 0.f;
        #pragma unroll
        for (int e = 0; e < 16; ++e) {
            int n = lane + 64 * e;
            acc = fmaf(bf2f(wrow[n]), sig_l[n], acc);
        }
        #pragma unroll
        for (int off = 32; off; off >>= 1) acc += __shfl_xor(acc, off);
        if (lane == 0) hid_l[j] = geluf(acc + mb1[j]);
    }
    __syncthreads();
    for (int ii = 0; ii < 4; ++ii) {
        int i = sub * 64 + w * 4 + ii;
        const ushort* wrow = mW2T + (long)i * 512;
        float acc = 0.f;
        #pragma unroll
        for (int e = 0; e < 8; ++e) {
            int n = lane + 64 * e;
            acc = fmaf(bf2f(wrow[n]), hid_l[n], acc);
        }
        #pragma unroll
        for (int off = 32; off; off >>= 1) acc += __shfl_xor(acc, off);
        if (lane == 0) {
            float v = base_metric[i] + 0.1f * (acc + mb2[i]);
            float sp = fmaxf(v, 0.f) + log1pf(expf(-fabsf(v)));
            metric[b * 1024 + i] = sp + 1e-6f;
        }
    }
}

// ======== causal K-window via MFMA (norm-trick QK^T, banded softmax, MFMA PV+heb) ====
#define QLD 136
#define QLDU 68
#define VLD 72
#define PLD 72
#define CLD 132

__global__ __launch_bounds__(256) void window_kernel(
    const ushort* __restrict__ qs, const ushort* __restrict__ vs,
    const float* __restrict__ metric, const ushort* __restrict__ hebT,
    ushort* __restrict__ gated) {
    int tile = blockIdx.x, h = blockIdx.y, b = blockIdx.z;
    int t0 = tile * 16;
    int tid = threadIdx.x;
    __shared__ __align__(16) ushort Qt[48 * QLD];
    __shared__ __align__(16) ushort Qr[16 * QLD];
    __shared__ __align__(16) ushort Vt[128 * VLD];
    __shared__ __align__(16) ushort P[16 * PLD];
    __shared__ float ctx[16 * CLD];
    __shared__ float ns[48], invn_l[16], part[3][16], smf[128];

    if (tid < 128) smf[tid] = sqrtf(metric[(b * H_ + h) * HD_ + tid]);
    if (tid < 128) { int t = tid >> 3, c = tid & 7; if (t < 16) ((uint*)P)[t * 36 + 24 + c] = 0; }
    __syncthreads();

    for (int i = tid; i < 48 * 64; i += 256) {
        int r = i >> 6, c = i & 63;
        int grow = t0 - 31 + r;
        uint qv = 0;
        if (r < 47 && grow >= 0)
            qv = ((const uint*)qs)[(((long)(b * T_ + grow) * N_ + h * HD_) >> 1) + c];
        float q0 = bf2f((ushort)(qv & 0xffff)) * smf[2 * c];
        float q1 = bf2f((ushort)(qv >> 16)) * smf[2 * c + 1];
        ((uint*)Qt)[r * QLDU + c] = (uint)f2bf(q0) | ((uint)f2bf(q1) << 16);
        if (r >= 31 && r < 47) ((uint*)Qr)[(r - 31) * QLDU + c] = qv;
    }
    for (int i = tid; i < 32 * 64; i += 256) {
        int r2 = i >> 6, c = i & 63;
        int ra = 2 * r2, rb_ = 2 * r2 + 1;
        int ga = t0 - 31 + ra, gb = t0 - 31 + rb_;
        uint v0 = 0, v1 = 0;
        if (ra < 47 && ga >= 0)
            v0 = ((const uint*)vs)[(((long)(b * T_ + ga) * N_ + h * HD_) >> 1) + c];
        if (rb_ < 47 && gb >= 0)
            v1 = ((const uint*)vs)[(((long)(b * T_ + gb) * N_ + h * HD_) >> 1) + c];
        ((uint*)Vt)[(2 * c) * 36 + r2]     = (v0 & 0xffff) | ((v1 & 0xffff) << 16);
        ((uint*)Vt)[(2 * c + 1) * 36 + r2] = (v0 >> 16) | (v1 & 0xffff0000u);
    }
    __syncthreads();

    int w = tid >> 6, lane = tid & 63;
    int lc = lane & 15, lr = lane >> 4;

    for (int rr = 0; rr < 16; ++rr) {
        int row = w * 16 + rr;
        uint u = (row < 48) ? ((uint*)Qt)[row * QLDU + lane]
                            : ((uint*)Qr)[(row - 48) * QLDU + lane];
        float a0 = bf2f((ushort)(u & 0xffff)), a1 = bf2f((ushort)(u >> 16));
        float nv = a0 * a0 + a1 * a1;
        #pragma unroll
        for (int off = 32; off; off >>= 1) nv += __shfl_xor(nv, off);
        if (lane == 0) {
            if (row < 48) ns[row] = nv;
            else invn_l[row - 48] = 1.0f / fmaxf(sqrtf(nv), 1e-12f);
        }
    }
    __syncthreads();

    f32x4 accS = {};
    if (w < 3) {
        #pragma unroll
        for (int k = 0; k < 4; ++k) {
            short8v a = *(const short8v*)&Qt[(w * 16 + lc) * QLD + k * 32 + lr * 8];
            short8v bf_ = *(const short8v*)&Qt[(31 + lc) * QLD + k * 32 + lr * 8];
            accS = __builtin_amdgcn_mfma_f32_16x16x32_bf16(a, bf_, accS, 0, 0, 0);
        }
    }
    f32x4 accH[2] = {};
    const ushort* hb = hebT + (long)h * HD_ * HD_;
    #pragma unroll
    for (int nt = 0; nt < 2; ++nt)
        #pragma unroll
        for (int k = 0; k < 4; ++k) {
            short8v a = *(const short8v*)&Qr[lc * QLD + k * 32 + lr * 8];
            short8v bf_ = *(const short8v*)&hb[(long)((w * 2 + nt) * 16 + lc) * HD_ + k * 32 + lr * 8];
            accH[nt] = __builtin_amdgcn_mfma_f32_16x16x32_bf16(a, bf_, accH[nt], 0, 0, 0);
        }
    #pragma unroll
    for (int nt = 0; nt < 2; ++nt)
        #pragma unroll
        for (int j = 0; j < 4; ++j) {
            int t = lr * 4 + j;
            ctx[t * CLD + (w * 2 + nt) * 16 + lc] = accH[nt][j] * invn_l[t];
        }
    float wgt[4];
    if (w < 3) {
        float nt_ = ns[31 + lc];
        float psum = 0.f;
        #pragma unroll
        for (int j = 0; j < 4; ++j) {
            int s = w * 16 + lr * 4 + j;
            float val = fmaxf(nt_ + ns[s] - 2.0f * accS[j], 0.0f) + 1e-8f;
            bool band = (s >= lc) && (s <= lc + 31);
            wgt[j] = band ? __expf(-sqrtf(val)) : 0.0f;
            psum += wgt[j];
        }
        psum += __shfl_xor(psum, 16);
        psum += __shfl_xor(psum, 32);
        if (lane < 16) part[w][lane] = psum;
    }
    __syncthreads();
    if (w < 3) {
        float inv = 1.0f / (part[0][lc] + part[1][lc] + part[2][lc] + 1e-8f);
        uint lo = (uint)f2bf(wgt[0] * inv) | ((uint)f2bf(wgt[1] * inv) << 16);
        uint hi = (uint)f2bf(wgt[2] * inv) | ((uint)f2bf(wgt[3] * inv) << 16);
        uint2 pk = {lo, hi};
        *(uint2*)&P[lc * PLD + w * 16 + lr * 4] = pk;
    }
    __syncthreads();
    f32x4 accP[2] = {};
    #pragma unroll
    for (int mt = 0; mt < 2; ++mt)
        #pragma unroll
        for (int k = 0; k < 2; ++k) {
            short8v a = *(const short8v*)&Vt[((w * 2 + mt) * 16 + lc) * VLD + k * 32 + lr * 8];
            short8v bf_ = *(const short8v*)&P[lc * PLD + k * 32 + lr * 8];
            accP[mt] = __builtin_amdgcn_mfma_f32_16x16x32_bf16(a, bf_, accP[mt], 0, 0, 0);
        }
    #pragma unroll
    for (int mt = 0; mt < 2; ++mt)
        #pragma unroll
        for (int j = 0; j < 4; ++j) {
            int e = (w * 2 + mt) * 16 + lr * 4 + j;
            ctx[lc * CLD + e] += accP[mt][j];
        }
    __syncthreads();
    {
        int t = tid >> 4, g = tid & 15;
        uint4 qu = *(const uint4*)&((const uint*)Qr)[t * QLDU + g * 4];
        const float* crow = &ctx[t * CLD + g * 8];
        uint qa[4] = {qu.x, qu.y, qu.z, qu.w};
        uint outp[4];
        #pragma unroll
        for (int q4 = 0; q4 < 4; ++q4) {
            float e0 = bf2f((ushort)(qa[q4] & 0xffff)) * crow[2 * q4];
            float e1 = bf2f((ushort)(qa[q4] >> 16))   * crow[2 * q4 + 1];
            outp[q4] = (uint)f2bf(e0) | ((uint)f2bf(e1) << 16);
        }
        *(uint4*)&gated[(long)(b * T_ + t0 + t) * N_ + h * HD_ + g * 8] = *(uint4*)outp;
    }
}

extern "C" void kernel_launch(void* const* d_in, const int* in_sizes, int n_in,
                              void* d_out, int out_size, void* d_ws, size_t ws_size,
                              hipStream_t stream) {
    const int*   tokens      = (const int*)  d_in[0];
    const float* emb         = (const float*)d_in[1];
    const float* field_init  = (const float*)d_in[2];
    const float* Wq          = (const float*)d_in[3];
    const float* Wv          = (const float*)d_in[4];
    const float* mW1         = (const float*)d_in[5];
    const float* mb1         = (const float*)d_in[6];
    const float* mW2         = (const float*)d_in[7];
    const float* mb2         = (const float*)d_in[8];
    const float* base_metric = (const float*)d_in[9];
    const float* decoder     = (const float*)d_in[10];
    const float* hebbian     = (const float*)d_in[11];
    const float* fW1         = (const float*)d_in[12];
    const float* fb1         = (const float*)d_in[13];
    const float* fW2         = (const float*)d_in[14];
    const float* fb2         = (const float*)d_in[15];
    const float* g1          = (const float*)d_in[16];
    const float* b1          = (const float*)d_in[17];
    const float* g2          = (const float*)d_in[18];
    const float* b2          = (const float*)d_in[19];
    const float* gf          = (const float*)d_in[20];
    const float* bf          = (const float*)d_in[21];
    const float* Wl          = (const float*)d_in[22];
    const float* bl          = (const float*)d_in[23];
    float* out = (float*)d_out;

    char* wp = (char*)d_ws;
    auto alloc = [&](size_t bytes) { char* p = wp; wp += (bytes + 255) & ~255UL; return p; };
    float*  x        = (float*) alloc(524288 * 4);
    ushort* y1_bf    = (ushort*)alloc(524288 * 2);
    ushort* y2_bf    = (ushort*)alloc(524288 * 2);
    ushort* yf_bf    = (ushort*)alloc(524288 * 2);
    ushort* qs_bf    = (ushort*)alloc(2097152 * 2);
    ushort* vs_bf    = (ushort*)alloc(2097152 * 2);
    ushort* gated_bf = (ushort*)alloc(2097152 * 2);
    ushort* ffnh_bf  = (ushort*)alloc(2097152 * 2);
    float*  dx       = (float*) alloc(524288 * 4);
    ushort* WqT      = (ushort*)alloc(262144 * 2);
    ushort* WvT      = (ushort*)alloc(262144 * 2);
    ushort* decT     = (ushort*)alloc(262144 * 2);
    ushort* fW1T     = (ushort*)alloc(262144 * 2);
    ushort* fW2T     = (ushort*)alloc(262144 * 2);
    ushort* mW1T     = (ushort*)alloc(524288 * 2);
    ushort* mW2T     = (ushort*)alloc(524288 * 2);
    ushort* hebT     = (ushort*)alloc(131072 * 2);
    ushort* WlT      = (ushort*)alloc((size_t)VOCAB_ * 256 * 2);
    float*  ps       = (float*) alloc(16 * 1024 * 4);
    float*  ps8      = (float*) alloc(16 * 1024 * 4);
    float*  metricb  = (float*) alloc(2048 * 4);

    TcastBatch tb;
    const float* tin[9]  = {Wq, Wv, decoder, fW1, fW2, mW1, mW2, hebbian, Wl};
    ushort*      tout[9] = {WqT, WvT, decT, fW1T, fW2T, mW1T, mW2T, hebT, WlT};
    long tinS[9]  = {256 * 128, 256 * 128, 0, 0, 0, 0, 0, 128 * 128, 0};
    long toutS[9] = {128 * 256, 128 * 256, 0, 0, 0, 0, 0, 128 * 128, 0};
    int tR[9] = {256, 256, 1024, 256, 1024, 1024, 512, 128, 256};
    int tC[9] = {128, 128, 256, 1024, 256, 512, 1024, 128, VOCAB_};
    int cum = 0;
    tb.cum[0] = 0;
    for (int i = 0; i < 9; ++i) {
        tb.in[i] = tin[i]; tb.out[i] = tout[i];
        tb.inS[i] = tinS[i]; tb.outS[i] = toutS[i];
        tb.R[i] = tR[i]; tb.C[i] = tC[i];
        tb.cb[i] = tC[i] / 64; tb.rb[i] = tR[i] / 64;
        int zc = (i == 0 || i == 1 || i == 7) ? 8 : 1;
        cum += tb.cb[i] * tb.rb[i] * zc;
        tb.cum[i + 1] = cum;
    }

    prep_kernel<<<B_ * T_ + cum, 256, 0, stream>>>(
        tb, tokens, emb, field_init, g1, b1, g2, b2, x, y1_bf, y2_bf);

    for (int step = 0; step < 2; ++step) {
        if (step == 1)
            ln_kernel<<<B_ * T_, 256, 0, stream>>>(
                x, dx, g1, b1, g2, b2, y1_bf, y2_bf);
        gemm3_kernel<<<dim3(8, 16, 3), 256, 0, stream>>>(
            y1_bf, y2_bf, WqT, WvT, fW1T, fb1, qs_bf, vs_bf, ffnh_bf, ps, ps8);
        mlpf_kernel<<<32, 1024, 0, stream>>>(
            ps, ps8, mW1T, mb1, mW2T, mb2, base_metric, metricb);
        window_kernel<<<dim3(T_ / 16, H_, B_), 256, 0, stream>>>(
            qs_bf, vs_bf, metricb, hebT, gated_bf);
        gemm2b_kernel<<<dim3(4, 32), 256, 0, stream>>>(
            gated_bf, ffnh_bf, decT, fW2T, fb2, dx);
    }
    ln_kernel<<<B_ * T_, 256, 0, stream>>>(
        x, dx, gf, bf, nullptr, nullptr, yf_bf, nullptr);
    vocab_kernel<<<4000, 256, 0, stream>>>(yf_bf, WlT, bl, out);
}

// Round 12
// 307.159 us; speedup vs baseline: 1.3107x; 1.3107x over previous
//
#include <hip/hip_runtime.h>
#include <hip/hip_bf16.h>
#include <math.h>

#define B_ 2
#define T_ 1024
#define D_ 256
#define N_ 1024
#define H_ 8
#define HD_ 128
#define K_ 32
#define VOCAB_ 32000

typedef __attribute__((ext_vector_type(8))) short short8v;
typedef __attribute__((ext_vector_type(4))) float f32x4;

static __device__ __forceinline__ float geluf(float x) {
    return 0.5f * x * (1.0f + erff(x * 0.70710678118654752f));
}

static __device__ __forceinline__ ushort f2bf(float f) {
    unsigned u = __builtin_bit_cast(unsigned, f);
    u += 0x7fff + ((u >> 16) & 1);
    return (ushort)(u >> 16);
}

static __device__ __forceinline__ float bf2f(ushort u) {
    unsigned v = ((unsigned)u) << 16;
    return __builtin_bit_cast(float, v);
}

// ---------------- fused embed + quantized RoPE + dual LayerNorm ----------------
__global__ void embed_rope_ln_kernel(const int* __restrict__ tokens,
                                     const float* __restrict__ emb,
                                     const float* __restrict__ field_init,
                                     const float* __restrict__ g1, const float* __restrict__ b1,
                                     const float* __restrict__ g2, const float* __restrict__ b2,
                                     float* __restrict__ x,
                                     ushort* __restrict__ y1, ushort* __restrict__ y2) {
    int bt = blockIdx.x;
    int d = threadIdx.x;
    int t = bt & (T_ - 1);
    int tok = tokens[bt];
    float v = emb[(long)tok * D_ + d] + field_init[d];
    float partner = __shfl_xor(v, 1);
    float rot = (d & 1) ? partner : -partner;
    float freq = exp2f(-0.0625f * (float)(d & ~1)) * (1.0f / 6.283185307179586f);
    float ph = fmodf((float)t * freq, 1.0f) * 6.283185307179586f;
    v = v * cosf(ph) + rot * sinf(ph);
    long i = (long)bt * D_ + d;
    x[i] = v;
    __shared__ float red[4];
    int lane = d & 63, wid = d >> 6;
    float s = v;
    #pragma unroll
    for (int off = 32; off; off >>= 1) s += __shfl_xor(s, off);
    if (lane == 0) red[wid] = s;
    __syncthreads();
    float mu = (red[0] + red[1] + red[2] + red[3]) * (1.0f / D_);
    float dv = v - mu;
    float s2 = dv * dv;
    #pragma unroll
    for (int off = 32; off; off >>= 1) s2 += __shfl_xor(s2, off);
    __syncthreads();
    if (lane == 0) red[wid] = s2;
    __syncthreads();
    float var = (red[0] + red[1] + red[2] + red[3]) * (1.0f / D_);
    float rstd = rsqrtf(var + 1e-5f);
    float nv = dv * rstd;
    y1[i] = f2bf(nv * g1[d] + b1[d]);
    y2[i] = f2bf(nv * g2[d] + b2[d]);
}

// ---------------- LayerNorm (+ residual add) -> bf16 outputs ----------------
__global__ void ln_kernel(float* __restrict__ x,
                          const float* __restrict__ addA, const float* __restrict__ addB,
                          const float* __restrict__ g1, const float* __restrict__ b1,
                          const float* __restrict__ g2, const float* __restrict__ b2,
                          ushort* __restrict__ y1, ushort* __restrict__ y2) {
    int row = blockIdx.x;
    int d = threadIdx.x;
    long i = (long)row * D_ + d;
    float v = x[i] + addA[i] + addB[i];
    x[i] = v;
    __shared__ float red[4];
    int lane = d & 63, wid = d >> 6;
    float s = v;
    #pragma unroll
    for (int off = 32; off; off >>= 1) s += __shfl_xor(s, off);
    if (lane == 0) red[wid] = s;
    __syncthreads();
    float mu = (red[0] + red[1] + red[2] + red[3]) * (1.0f / D_);
    float dv = v - mu;
    float s2 = dv * dv;
    #pragma unroll
    for (int off = 32; off; off >>= 1) s2 += __shfl_xor(s2, off);
    __syncthreads();
    if (lane == 0) red[wid] = s2;
    __syncthreads();
    float var = (red[0] + red[1] + red[2] + red[3]) * (1.0f / D_);
    float rstd = rsqrtf(var + 1e-5f);
    float nv = dv * rstd;
    y1[i] = f2bf(nv * g1[d] + b1[d]);
    if (y2) y2[i] = f2bf(nv * g2[d] + b2[d]);
}

// ---------------- transpose-cast tile body ----------------
static __device__ __forceinline__ void tcast_tile(
    const float* __restrict__ in, ushort* __restrict__ out,
    int R, int C, int ry, int cx) {
    __shared__ float sm[64][65];
    int r0 = ry * 64, c0 = cx * 64;
    int tx = threadIdx.x & 63, ty = threadIdx.x >> 6;
    #pragma unroll
    for (int i = 0; i < 16; ++i) {
        int r = i * 4 + ty;
        sm[r][tx] = in[(long)(r0 + r) * C + c0 + tx];
    }
    __syncthreads();
    #pragma unroll
    for (int i = 0; i < 16; ++i) {
        int c = i * 4 + ty;
        out[(long)(c0 + c) * R + r0 + tx] = f2bf(sm[tx][c]);
    }
}

__global__ __launch_bounds__(256) void tcast_kernel(
    const float* __restrict__ in, ushort* __restrict__ out, int R, int C) {
    tcast_tile(in, out, R, C, blockIdx.y, blockIdx.x);
}

struct TcastBatch {
    const float* in[8];
    ushort* out[8];
    long inS[8], outS[8];
    int cb[8], rb[8], R[8], C[8];
    int cum[9];
};

__global__ __launch_bounds__(256) void tcast_all_kernel(TcastBatch tb) {
    int bid = blockIdx.x;
    int d = 0;
    #pragma unroll
    for (int i = 0; i < 8; ++i) if (bid >= tb.cum[i + 1]) d = i + 1;
    int local = bid - tb.cum[d];
    int bpz = tb.cb[d] * tb.rb[d];
    int z = local / bpz;
    int rem = local - z * bpz;
    int cx = rem % tb.cb[d], ry = rem / tb.cb[d];
    tcast_tile(tb.in[d] + z * tb.inS[d], tb.out[d] + z * tb.outS[d],
               tb.R[d], tb.C[d], ry, cx);
}

// ================= 128x128 MFMA core, BK=64; LDS-staged epilogue; optional sig =====
#define LDK 72
#define CSTR 132

template<int ACT, int OUTBF, int SIG>
__device__ __forceinline__ void gemm128_core(
    const ushort* __restrict__ A, int lda,
    const ushort* __restrict__ Bt, int ldb,
    const float* __restrict__ bias, void* __restrict__ Cout, int ldc,
    int Kd, int bx, int by,
    float* __restrict__ psOut, float* __restrict__ ps8Out) {
    __shared__ __align__(16) ushort As[128 * LDK];
    __shared__ __align__(16) ushort Bs[128 * LDK];
    int tid = threadIdx.x;
    int wid = tid >> 6, lane = tid & 63;
    int brow = by * 128, bcol = bx * 128;
    int wr = wid >> 1, wc = wid & 1;
    f32x4 acc[4][4] = {};
    for (int k0 = 0; k0 < Kd; k0 += 64) {
        __syncthreads();
        #pragma unroll
        for (int j = 0; j < 4; ++j) {
            int idx = tid + j * 256;
            int r = idx >> 3, sgm = idx & 7;
            *(short8v*)&As[r * LDK + sgm * 8] =
                *(const short8v*)&A[(long)(brow + r) * lda + k0 + sgm * 8];
            *(short8v*)&Bs[r * LDK + sgm * 8] =
                *(const short8v*)&Bt[(long)(bcol + r) * ldb + k0 + sgm * 8];
        }
        __syncthreads();
        #pragma unroll
        for (int kk = 0; kk < 2; ++kk) {
            short8v af[4], bfv[4];
            #pragma unroll
            for (int m = 0; m < 4; ++m)
                af[m] = *(const short8v*)&As[(wr * 64 + m * 16 + (lane & 15)) * LDK + kk * 32 + (lane >> 4) * 8];
            #pragma unroll
            for (int n = 0; n < 4; ++n)
                bfv[n] = *(const short8v*)&Bs[(wc * 64 + n * 16 + (lane & 15)) * LDK + kk * 32 + (lane >> 4) * 8];
            #pragma unroll
            for (int m = 0; m < 4; ++m)
                #pragma unroll
                for (int n = 0; n < 4; ++n)
                    acc[m][n] = __builtin_amdgcn_mfma_f32_16x16x32_bf16(af[m], bfv[n], acc[m][n], 0, 0, 0);
        }
    }
    float* Cs = (float*)As;
    float cs = 0.f, cs8 = 0.f;
    #pragma unroll
    for (int chunk = 0; chunk < 4; ++chunk) {
        __syncthreads();
        if (wr == (chunk >> 1)) {
            #pragma unroll
            for (int mm = 0; mm < 2; ++mm) {
                int m = (chunk & 1) * 2 + mm;
                int lr0 = mm * 16 + ((lane >> 4) << 2);
                #pragma unroll
                for (int n = 0; n < 4; ++n) {
                    int lcol = wc * 64 + n * 16 + (lane & 15);
                    #pragma unroll
                    for (int j = 0; j < 4; ++j)
                        Cs[(lr0 + j) * CSTR + lcol] = acc[m][n][j];
                }
            }
        }
        __syncthreads();
        int lrow = tid >> 3, f4 = tid & 7;
        long grow = brow + chunk * 32 + lrow;
        if (OUTBF) {
            #pragma unroll
            for (int u = 0; u < 2; ++u) {
                int c0i = (f4 + u * 8) * 8;
                uint pk[4];
                #pragma unroll
                for (int q = 0; q < 4; ++q) {
                    int cc = c0i + 2 * q;
                    float v0 = Cs[lrow * CSTR + cc]     + (bias ? bias[bcol + cc] : 0.0f);
                    float v1 = Cs[lrow * CSTR + cc + 1] + (bias ? bias[bcol + cc + 1] : 0.0f);
                    if (ACT == 1) { v0 = fmaxf(v0, 0.0f); v1 = fmaxf(v1, 0.0f); }
                    else if (ACT == 2) { v0 = geluf(v0); v1 = geluf(v1); }
                    pk[q] = (uint)f2bf(v0) | ((uint)f2bf(v1) << 16);
                }
                *(uint4*)&((ushort*)Cout)[grow * ldc + bcol + c0i] = *(uint4*)pk;
            }
        } else {
            #pragma unroll
            for (int u = 0; u < 4; ++u) {
                int c0i = (f4 + u * 8) * 4;
                float vv[4];
                #pragma unroll
                for (int q = 0; q < 4; ++q) {
                    float v = Cs[lrow * CSTR + c0i + q] + (bias ? bias[bcol + c0i + q] : 0.0f);
                    if (ACT == 1) v = fmaxf(v, 0.0f);
                    else if (ACT == 2) v = geluf(v);
                    vv[q] = v;
                }
                *(float4*)&((float*)Cout)[grow * ldc + bcol + c0i] = *(float4*)vv;
            }
        }
        if (SIG && tid < 128) {
            #pragma unroll
            for (int r = 0; r < 32; ++r) {
                float vr = fmaxf(Cs[r * CSTR + tid], 0.0f);
                cs += vr;
                if ((r & 7) == 0) cs8 += vr;
            }
        }
    }
    if (SIG && tid < 128) {
        psOut[by * 1024 + bcol + tid] = cs;
        ps8Out[by * 1024 + bcol + tid] = cs8;
    }
}

// batched qs/vs/ffn1 (bf16 out); z=0 also emits sig partial sums
__global__ __launch_bounds__(256) void gemm3_kernel(
    const ushort* __restrict__ y1, const ushort* __restrict__ y2,
    const ushort* __restrict__ WqT, const ushort* __restrict__ WvT, const ushort* __restrict__ fW1T,
    const float* __restrict__ fb1,
    ushort* __restrict__ qs, ushort* __restrict__ vs, ushort* __restrict__ ffnh,
    float* __restrict__ ps, float* __restrict__ ps8) {
    int z = blockIdx.z;
    if (z == 0)
        gemm128_core<1, 1, 1>(y1, 256, WqT, 256, nullptr, qs, 1024, 256,
                              blockIdx.x, blockIdx.y, ps, ps8);
    else if (z == 1)
        gemm128_core<1, 1, 0>(y1, 256, WvT, 256, nullptr, vs, 1024, 256,
                              blockIdx.x, blockIdx.y, nullptr, nullptr);
    else
        gemm128_core<2, 1, 0>(y2, 256, fW1T, 256, fb1, ffnh, 1024, 256,
                              blockIdx.x, blockIdx.y, nullptr, nullptr);
}

// vocab projection with XCD-chunked block swizzle (grid 4000 = 8*500)
__global__ __launch_bounds__(256) void vocab_kernel(
    const ushort* __restrict__ yf, const ushort* __restrict__ WlT,
    const float* __restrict__ bl, float* __restrict__ out) {
    int g = blockIdx.x;
    int nid = (g & 7) * 500 + (g >> 3);
    gemm128_core<0, 0, 0>(yf, 256, WlT, 256, bl, out, VOCAB_, 256,
                          nid >> 4, nid & 15, nullptr, nullptr);
}

// ================= 64x64 MFMA core for N=256 GEMMs (decoder + FFN2) =============
__global__ __launch_bounds__(256) void gemm2_kernel(
    const ushort* __restrict__ gated, const ushort* __restrict__ ffnh,
    const ushort* __restrict__ decT, const ushort* __restrict__ fW2T,
    const float* __restrict__ fb2,
    float* __restrict__ dec_out, float* __restrict__ ffn_out) {
    int z = blockIdx.z;
    const ushort* A = z ? ffnh : gated;
    const ushort* Bt = z ? fW2T : decT;
    const float* bias = z ? fb2 : nullptr;
    float* C = z ? ffn_out : dec_out;
    const int Kd = 1024, N = 256;
    __shared__ __align__(16) ushort As[64 * LDK];
    __shared__ __align__(16) ushort Bs[64 * LDK];
    int tid = threadIdx.x;
    int wid = tid >> 6, lane = tid & 63;
    int brow = blockIdx.y * 64, bcol = blockIdx.x * 64;
    int wr = wid >> 1, wc = wid & 1;
    f32x4 acc[2][2] = {};
    for (int k0 = 0; k0 < Kd; k0 += 64) {
        __syncthreads();
        #pragma unroll
        for (int j = 0; j < 2; ++j) {
            int idx = tid + j * 256;
            int r = idx >> 3, sgm = idx & 7;
            *(short8v*)&As[r * LDK + sgm * 8] =
                *(const short8v*)&A[(long)(brow + r) * Kd + k0 + sgm * 8];
            *(short8v*)&Bs[r * LDK + sgm * 8] =
                *(const short8v*)&Bt[(long)(bcol + r) * Kd + k0 + sgm * 8];
        }
        __syncthreads();
        #pragma unroll
        for (int kk = 0; kk < 2; ++kk) {
            short8v af[2], bfv[2];
            #pragma unroll
            for (int m = 0; m < 2; ++m)
                af[m] = *(const short8v*)&As[(wr * 32 + m * 16 + (lane & 15)) * LDK + kk * 32 + (lane >> 4) * 8];
            #pragma unroll
            for (int n = 0; n < 2; ++n)
                bfv[n] = *(const short8v*)&Bs[(wc * 32 + n * 16 + (lane & 15)) * LDK + kk * 32 + (lane >> 4) * 8];
            #pragma unroll
            for (int m = 0; m < 2; ++m)
                #pragma unroll
                for (int n = 0; n < 2; ++n)
                    acc[m][n] = __builtin_amdgcn_mfma_f32_16x16x32_bf16(af[m], bfv[n], acc[m][n], 0, 0, 0);
        }
    }
    int r0 = brow + wr * 32 + ((lane >> 4) << 2);
    int c0 = bcol + wc * 32 + (lane & 15);
    #pragma unroll
    for (int n = 0; n < 2; ++n) {
        int col = c0 + n * 16;
        float bv = bias ? bias[col] : 0.0f;
        #pragma unroll
        for (int m = 0; m < 2; ++m)
            #pragma unroll
            for (int j = 0; j < 4; ++j)
                C[(long)(r0 + m * 16 + j) * N + col] = acc[m][n][j] + bv;
    }
}

// ---------------- metric MLP stage 1 (fused ps reduction) ----------------
__global__ __launch_bounds__(256) void mlp1_kernel(
    const float* __restrict__ ps, const float* __restrict__ ps8,
    const ushort* __restrict__ mW1T, const float* __restrict__ mb1,
    float* __restrict__ hid) {
    int blk = blockIdx.x;
    int b = blk >> 7;
    __shared__ float sig_l[1024];
    int tid = threadIdx.x;
    for (int c = tid; c < 1024; c += 256) {
        float s = 0.f, s8 = 0.f;
        #pragma unroll
        for (int by8 = 0; by8 < 8; ++by8) {
            s += ps[(b * 8 + by8) * 1024 + c];
            s8 += ps8[(b * 8 + by8) * 1024 + c];
        }
        sig_l[c] = s * (1.0f / 1024.0f) + 0.5f * s8 * (1.0f / 128.0f);
    }
    __syncthreads();
    int wv = tid >> 6, lane = tid & 63;
    int j = (blk & 127) * 4 + wv;
    const ushort* wrow = mW1T + (long)j * 1024;
    float acc = 0.f;
    #pragma unroll
    for (int c2 = 0; c2 < 4; ++c2) {
        int n0 = c2 * 256 + lane * 4;
        float4 sv = *(const float4*)&sig_l[n0];
        ushort4 w4 = *(const ushort4*)&wrow[n0];
        acc += bf2f(w4.x) * sv.x + bf2f(w4.y) * sv.y
             + bf2f(w4.z) * sv.z + bf2f(w4.w) * sv.w;
    }
    #pragma unroll
    for (int off = 32; off; off >>= 1) acc += __shfl_xor(acc, off);
    if (lane == 0) hid[b * 512 + j] = geluf(acc + mb1[j]);
}

__global__ __launch_bounds__(256) void mlp2_kernel(
    const float* __restrict__ hid, const ushort* __restrict__ mW2T,
    const float* __restrict__ mb2, const float* __restrict__ base_metric,
    float* __restrict__ metric) {
    int widx = blockIdx.x * 4 + (threadIdx.x >> 6);
    int b = widx >> 10, i = widx & 1023;
    int lane = threadIdx.x & 63;
    const float* hd = hid + b * 512;
    const ushort* w = mW2T + (long)i * 512;
    int j0 = lane * 8;
    short8v wv = *(const short8v*)&w[j0];
    float4 h0 = *(const float4*)&hd[j0];
    float4 h1 = *(const float4*)&hd[j0 + 4];
    float acc = bf2f((ushort)wv[0]) * h0.x + bf2f((ushort)wv[1]) * h0.y
              + bf2f((ushort)wv[2]) * h0.z + bf2f((ushort)wv[3]) * h0.w
              + bf2f((ushort)wv[4]) * h1.x + bf2f((ushort)wv[5]) * h1.y
              + bf2f((ushort)wv[6]) * h1.z + bf2f((ushort)wv[7]) * h1.w;
    #pragma unroll
    for (int off = 32; off; off >>= 1) acc += __shfl_xor(acc, off);
    if (lane == 0) {
        float v = base_metric[i] + 0.1f * (acc + mb2[i]);
        float sp = fmaxf(v, 0.f) + log1pf(expf(-fabsf(v)));
        metric[b * 1024 + i] = sp + 1e-6f;
    }
}

// ======== causal K-window via MFMA (norm-trick QK^T, banded softmax, MFMA PV+heb) ====
#define QLD 136
#define QLDU 68
#define VLD 72
#define PLD 72
#define CLD 132

__global__ __launch_bounds__(256) void window_kernel(
    const ushort* __restrict__ qs, const ushort* __restrict__ vs,
    const float* __restrict__ metric, const ushort* __restrict__ hebT,
    ushort* __restrict__ gated) {
    int tile = blockIdx.x, h = blockIdx.y, b = blockIdx.z;
    int t0 = tile * 16;
    int tid = threadIdx.x;
    __shared__ __align__(16) ushort Qt[48 * QLD];
    __shared__ __align__(16) ushort Qr[16 * QLD];
    __shared__ __align__(16) ushort Vt[128 * VLD];
    __shared__ __align__(16) ushort P[16 * PLD];
    __shared__ float ctx[16 * CLD];
    __shared__ float ns[48], invn_l[16], part[3][16], smf[128];

    if (tid < 128) smf[tid] = sqrtf(metric[(b * H_ + h) * HD_ + tid]);
    if (tid < 128) { int t = tid >> 3, c = tid & 7; if (t < 16) ((uint*)P)[t * 36 + 24 + c] = 0; }
    __syncthreads();

    for (int i = tid; i < 48 * 64; i += 256) {
        int r = i >> 6, c = i & 63;
        int grow = t0 - 31 + r;
        uint qv = 0;
        if (r < 47 && grow >= 0)
            qv = ((const uint*)qs)[(((long)(b * T_ + grow) * N_ + h * HD_) >> 1) + c];
        float q0 = bf2f((ushort)(qv & 0xffff)) * smf[2 * c];
        float q1 = bf2f((ushort)(qv >> 16)) * smf[2 * c + 1];
        ((uint*)Qt)[r * QLDU + c] = (uint)f2bf(q0) | ((uint)f2bf(q1) << 16);
        if (r >= 31 && r < 47) ((uint*)Qr)[(r - 31) * QLDU + c] = qv;
    }
    for (int i = tid; i < 32 * 64; i += 256) {
        int r2 = i >> 6, c = i & 63;
        int ra = 2 * r2, rb_ = 2 * r2 + 1;
        int ga = t0 - 31 + ra, gb = t0 - 31 + rb_;
        uint v0 = 0, v1 = 0;
        if (ra < 47 && ga >= 0)
            v0 = ((const uint*)vs)[(((long)(b * T_ + ga) * N_ + h * HD_) >> 1) + c];
        if (rb_ < 47 && gb >= 0)
            v1 = ((const uint*)vs)[(((long)(b * T_ + gb) * N_ + h * HD_) >> 1) + c];
        ((uint*)Vt)[(2 * c) * 36 + r2]     = (v0 & 0xffff) | ((v1 & 0xffff) << 16);
        ((uint*)Vt)[(2 * c + 1) * 36 + r2] = (v0 >> 16) | (v1 & 0xffff0000u);
    }
    __syncthreads();

    int w = tid >> 6, lane = tid & 63;
    int lc = lane & 15, lr = lane >> 4;

    for (int rr = 0; rr < 16; ++rr) {
        int row = w * 16 + rr;
        uint u = (row < 48) ? ((uint*)Qt)[row * QLDU + lane]
                            : ((uint*)Qr)[(row - 48) * QLDU + lane];
        float a0 = bf2f((ushort)(u & 0xffff)), a1 = bf2f((ushort)(u >> 16));
        float nv = a0 * a0 + a1 * a1;
        #pragma unroll
        for (int off = 32; off; off >>= 1) nv += __shfl_xor(nv, off);
        if (lane == 0) {
            if (row < 48) ns[row] = nv;
            else invn_l[row - 48] = 1.0f / fmaxf(sqrtf(nv), 1e-12f);
        }
    }
    __syncthreads();

    f32x4 accS = {};
    if (w < 3) {
        #pragma unroll
        for (int k = 0; k < 4; ++k) {
            short8v a = *(const short8v*)&Qt[(w * 16 + lc) * QLD + k * 32 + lr * 8];
            short8v bf_ = *(const short8v*)&Qt[(31 + lc) * QLD + k * 32 + lr * 8];
            accS = __builtin_amdgcn_mfma_f32_16x16x32_bf16(a, bf_, accS, 0, 0, 0);
        }
    }
    f32x4 accH[2] = {};
    const ushort* hb = hebT + (long)h * HD_ * HD_;
    #pragma unroll
    for (int nt = 0; nt < 2; ++nt)
        #pragma unroll
        for (int k = 0; k < 4; ++k) {
            short8v a = *(const short8v*)&Qr[lc * QLD + k * 32 + lr * 8];
            short8v bf_ = *(const short8v*)&hb[(long)((w * 2 + nt) * 16 + lc) * HD_ + k * 32 + lr * 8];
            accH[nt] = __builtin_amdgcn_mfma_f32_16x16x32_bf16(a, bf_, accH[nt], 0, 0, 0);
        }
    #pragma unroll
    for (int nt = 0; nt < 2; ++nt)
        #pragma unroll
        for (int j = 0; j < 4; ++j) {
            int t = lr * 4 + j;
            ctx[t * CLD + (w * 2 + nt) * 16 + lc] = accH[nt][j] * invn_l[t];
        }
    float wgt[4];
    if (w < 3) {
        float nt_ = ns[31 + lc];
        float psum = 0.f;
        #pragma unroll
        for (int j = 0; j < 4; ++j) {
            int s = w * 16 + lr * 4 + j;
            float val = fmaxf(nt_ + ns[s] - 2.0f * accS[j], 0.0f) + 1e-8f;
            bool band = (s >= lc) && (s <= lc + 31);
            wgt[j] = band ? __expf(-sqrtf(val)) : 0.0f;
            psum += wgt[j];
        }
        psum += __shfl_xor(psum, 16);
        psum += __shfl_xor(psum, 32);
        if (lane < 16) part[w][lane] = psum;
    }
    __syncthreads();
    if (w < 3) {
        float inv = 1.0f / (part[0][lc] + part[1][lc] + part[2][lc] + 1e-8f);
        uint lo = (uint)f2bf(wgt[0] * inv) | ((uint)f2bf(wgt[1] * inv) << 16);
        uint hi = (uint)f2bf(wgt[2] * inv) | ((uint)f2bf(wgt[3] * inv) << 16);
        uint2 pk = {lo, hi};
        *(uint2*)&P[lc * PLD + w * 16 + lr * 4] = pk;
    }
    __syncthreads();
    f32x4 accP[2] = {};
    #pragma unroll
    for (int mt = 0; mt < 2; ++mt)
        #pragma unroll
        for (int k = 0; k < 2; ++k) {
            short8v a = *(const short8v*)&Vt[((w * 2 + mt) * 16 + lc) * VLD + k * 32 + lr * 8];
            short8v bf_ = *(const short8v*)&P[lc * PLD + k * 32 + lr * 8];
            accP[mt] = __builtin_amdgcn_mfma_f32_16x16x32_bf16(a, bf_, accP[mt], 0, 0, 0);
        }
    #pragma unroll
    for (int mt = 0; mt < 2; ++mt)
        #pragma unroll
        for (int j = 0; j < 4; ++j) {
            int e = (w * 2 + mt) * 16 + lr * 4 + j;
            ctx[lc * CLD + e] += accP[mt][j];
        }
    __syncthreads();
    {
        int t = tid >> 4, g = tid & 15;
        uint4 qu = *(const uint4*)&((const uint*)Qr)[t * QLDU + g * 4];
        const float* crow = &ctx[t * CLD + g * 8];
        uint qa[4] = {qu.x, qu.y, qu.z, qu.w};
        uint outp[4];
        #pragma unroll
        for (int q4 = 0; q4 < 4; ++q4) {
            float e0 = bf2f((ushort)(qa[q4] & 0xffff)) * crow[2 * q4];
            float e1 = bf2f((ushort)(qa[q4] >> 16))   * crow[2 * q4 + 1];
            outp[q4] = (uint)f2bf(e0) | ((uint)f2bf(e1) << 16);
        }
        *(uint4*)&gated[(long)(b * T_ + t0 + t) * N_ + h * HD_ + g * 8] = *(uint4*)outp;
    }
}

extern "C" void kernel_launch(void* const* d_in, const int* in_sizes, int n_in,
                              void* d_out, int out_size, void* d_ws, size_t ws_size,
                              hipStream_t stream) {
    const int*   tokens      = (const int*)  d_in[0];
    const float* emb         = (const float*)d_in[1];
    const float* field_init  = (const float*)d_in[2];
    const float* Wq          = (const float*)d_in[3];
    const float* Wv          = (const float*)d_in[4];
    const float* mW1         = (const float*)d_in[5];
    const float* mb1         = (const float*)d_in[6];
    const float* mW2         = (const float*)d_in[7];
    const float* mb2         = (const float*)d_in[8];
    const float* base_metric = (const float*)d_in[9];
    const float* decoder     = (const float*)d_in[10];
    const float* hebbian     = (const float*)d_in[11];
    const float* fW1         = (const float*)d_in[12];
    const float* fb1         = (const float*)d_in[13];
    const float* fW2         = (const float*)d_in[14];
    const float* fb2         = (const float*)d_in[15];
    const float* g1          = (const float*)d_in[16];
    const float* b1          = (const float*)d_in[17];
    const float* g2          = (const float*)d_in[18];
    const float* b2          = (const float*)d_in[19];
    const float* gf          = (const float*)d_in[20];
    const float* bf          = (const float*)d_in[21];
    const float* Wl          = (const float*)d_in[22];
    const float* bl          = (const float*)d_in[23];
    float* out = (float*)d_out;

    char* wp = (char*)d_ws;
    auto alloc = [&](size_t bytes) { char* p = wp; wp += (bytes + 255) & ~255UL; return p; };
    float*  x        = (float*) alloc(524288 * 4);
    ushort* y1_bf    = (ushort*)alloc(524288 * 2);
    ushort* y2_bf    = (ushort*)alloc(524288 * 2);
    ushort* yf_bf    = (ushort*)alloc(524288 * 2);
    ushort* qs_bf    = (ushort*)alloc(2097152 * 2);
    ushort* vs_bf    = (ushort*)alloc(2097152 * 2);
    ushort* gated_bf = (ushort*)alloc(2097152 * 2);
    ushort* ffnh_bf  = (ushort*)alloc(2097152 * 2);
    float*  dec_out  = (float*) alloc(524288 * 4);
    float*  ffn_out  = (float*) alloc(524288 * 4);
    ushort* WqT      = (ushort*)alloc(262144 * 2);
    ushort* WvT      = (ushort*)alloc(262144 * 2);
    ushort* decT     = (ushort*)alloc(262144 * 2);
    ushort* fW1T     = (ushort*)alloc(262144 * 2);
    ushort* fW2T     = (ushort*)alloc(262144 * 2);
    ushort* mW1T     = (ushort*)alloc(524288 * 2);
    ushort* mW2T     = (ushort*)alloc(524288 * 2);
    ushort* hebT     = (ushort*)alloc(131072 * 2);
    ushort* WlT      = (ushort*)alloc((size_t)VOCAB_ * 256 * 2);
    float*  ps       = (float*) alloc(16 * 1024 * 4);
    float*  ps8      = (float*) alloc(16 * 1024 * 4);
    float*  hid      = (float*) alloc(1024 * 4);
    float*  metricb  = (float*) alloc(2048 * 4);

    TcastBatch tb;
    const float* tin[8]  = {Wq, Wv, decoder, fW1, fW2, mW1, mW2, hebbian};
    ushort*      tout[8] = {WqT, WvT, decT, fW1T, fW2T, mW1T, mW2T, hebT};
    long tinS[8]  = {256 * 128, 256 * 128, 0, 0, 0, 0, 0, 128 * 128};
    long toutS[8] = {128 * 256, 128 * 256, 0, 0, 0, 0, 0, 128 * 128};
    int tR[8] = {256, 256, 1024, 256, 1024, 1024, 512, 128};
    int tC[8] = {128, 128, 256, 1024, 256, 512, 1024, 128};
    int cum = 0;
    tb.cum[0] = 0;
    for (int i = 0; i < 8; ++i) {
        tb.in[i] = tin[i]; tb.out[i] = tout[i];
        tb.inS[i] = tinS[i]; tb.outS[i] = toutS[i];
        tb.R[i] = tR[i]; tb.C[i] = tC[i];
        tb.cb[i] = tC[i] / 64; tb.rb[i] = tR[i] / 64;
        int zc = (i == 0 || i == 1 || i == 7) ? 8 : 1;
        cum += tb.cb[i] * tb.rb[i] * zc;
        tb.cum[i + 1] = cum;
    }
    tcast_all_kernel<<<cum, 256, 0, stream>>>(tb);

    embed_rope_ln_kernel<<<B_ * T_, 256, 0, stream>>>(
        tokens, emb, field_init, g1, b1, g2, b2, x, y1_bf, y2_bf);

    for (int step = 0; step < 2; ++step) {
        if (step == 1)
            ln_kernel<<<B_ * T_, 256, 0, stream>>>(
                x, dec_out, ffn_out, g1, b1, g2, b2, y1_bf, y2_bf);
        gemm3_kernel<<<dim3(8, 16, 3), 256, 0, stream>>>(
            y1_bf, y2_bf, WqT, WvT, fW1T, fb1, qs_bf, vs_bf, ffnh_bf, ps, ps8);
        mlp1_kernel<<<256, 256, 0, stream>>>(ps, ps8, mW1T, mb1, hid);
        mlp2_kernel<<<512, 256, 0, stream>>>(hid, mW2T, mb2, base_metric, metricb);
        window_kernel<<<dim3(T_ / 16, H_, B_), 256, 0, stream>>>(
            qs_bf, vs_bf, metricb, hebT, gated_bf);
        gemm2_kernel<<<dim3(4, 32, 2), 256, 0, stream>>>(
            gated_bf, ffnh_bf, decT, fW2T, fb2, dec_out, ffn_out);
    }
    ln_kernel<<<B_ * T_, 256, 0, stream>>>(
        x, dec_out, ffn_out, gf, bf, nullptr, nullptr, yf_bf, nullptr);
    tcast_kernel<<<dim3(500, 4), 256, 0, stream>>>(Wl, WlT, 256, VOCAB_);
    vocab_kernel<<<4000, 256, 0, stream>>>(yf_bf, WlT, bl, out);
}